// Round 13
// baseline (301.068 us; speedup 1.0000x reference)
//
#include <hip/hip_runtime.h>

// Sparse 3D conv (K=3, stride=2, pad=1), dense output, persistent tile-gather.
// No global atomics, no output memset. W staged ONCE per block into LDS as
// packed bf16 pairs, read conflict-free (ds_read_b32, consecutive banks).
// Inputs: features [N,32] f32, W [3,3,3,32,64] f32, coors [N,4] i32 (b,z,y,x).
// Output: [B,64,64,64,64] f32 flat, every element written exactly once.
// ws: [ map B*128^3 i32 | nxt N i32 ]

#define CIN   32
#define COUT  64
#define OUTD  64
#define IND   128
#define TILE  4
#define NTILE 16
#define NTH   512
#define GRID  1024
#define CAP   512       // pair list per tile (mean ~41, sigma ~6.4)
#define NPTS  128
#define NBLK  2048

// ---------- map build: voxel -> head of point-index chain (R3-verified) ----------
__global__ void build_map(const int4* __restrict__ coors, int* __restrict__ map,
                          int* __restrict__ nxt, int N)
{
    int i = blockIdx.x * 256 + threadIdx.x;
    if (i >= N) return;
    const int4 c = coors[i];                       // (b, z, y, x)
    const int v = ((c.x * IND + c.y) * IND + c.z) * IND + c.w;
    nxt[i] = atomicExch(&map[v], i);
}

// ---------- persistent gather: 8 tiles/block, W in LDS ----------
__global__ __launch_bounds__(NTH) void gather_p(
    const float* __restrict__ feats, const float* __restrict__ W,
    const int* __restrict__ map, const int* __restrict__ nxt,
    float* __restrict__ out, int nT)
{
    __shared__ unsigned wfu[27 * 16 * 64];   // 110.6 KB: [k][cp][ch] bf16-pair
    __shared__ float    accf[TILE*TILE*TILE*COUT]; // 16 KB
    __shared__ int      list[CAP];           // 2 KB
    __shared__ int      cnt;

    const int tid = threadIdx.x;
    const int ch  = tid & 63;
    const int wv  = tid >> 6;                // 0..7

    // Stage W once: pack c=2cp (low) and c=2cp+1 (high) bf16 RNE into one uint.
    for (int i = tid; i < 27 * 16 * 64; i += NTH) {
        const int chh = i & 63, cp = (i >> 6) & 15, k = i >> 10;
        const float* Ws = W + k * 2048 + (2 * cp) * 64 + chh;
        const unsigned u0 = __float_as_uint(Ws[0]);
        const unsigned u1 = __float_as_uint(Ws[64]);
        const unsigned b0 = (u0 + 0x7fffu + ((u0 >> 16) & 1u)) >> 16;
        const unsigned b1 = (u1 + 0x7fffu + ((u1 >> 16) & 1u)) >> 16;
        wfu[i] = b0 | (b1 << 16);
    }
    for (int i = tid; i < TILE*TILE*TILE*COUT; i += NTH) accf[i] = 0.f;
    if (tid == 0) cnt = 0;

    for (int tile = blockIdx.x; tile < nT; tile += GRID) {
        int t = tile;
        const int ox0 = (t & 15) * TILE; t >>= 4;
        const int oy0 = (t & 15) * TILE; t >>= 4;
        const int oz0 = (t & 15) * TILE; t >>= 4;
        const int b   = t;
        __syncthreads();                     // A: staging/rezero/cnt=0 visible

        // Phase 1: scan 9^3 input region (R3-verified enumeration).
        const int mapBase = b * IND * IND * IND;
        for (int idx = tid; idx < 9 * 9 * 9; idx += NTH) {
            const int rx = idx % 9, ry = (idx / 9) % 9, rz = idx / 81;
            const int px = 2 * ox0 - 1 + rx;
            const int py = 2 * oy0 - 1 + ry;
            const int pz = 2 * oz0 - 1 + rz;
            if ((unsigned)px >= IND || (unsigned)py >= IND || (unsigned)pz >= IND) continue;
            int j = map[mapBase + (pz * IND + py) * IND + px];
            if (j < 0) continue;

            const int kpx = (px + 1) & 1, ox1 = (px + 1 - kpx) >> 1;
            const int kpy = (py + 1) & 1, oy1 = (py + 1 - kpy) >> 1;
            const int kpz = (pz + 1) & 1, oz1 = (pz + 1 - kpz) >> 1;

            bool ok[8]; int pre[8];
            #pragma unroll
            for (int cz = 0; cz < 2; ++cz)
            #pragma unroll
            for (int cy = 0; cy < 2; ++cy)
            #pragma unroll
            for (int cx = 0; cx < 2; ++cx) {
                const int kz = kpz + 2 * cz, ky = kpy + 2 * cy, kx = kpx + 2 * cx;
                const int olz = oz1 - cz - oz0, oly = oy1 - cy - oy0, olx = ox1 - cx - ox0;
                const int ci = (cz * 2 + cy) * 2 + cx;
                ok[ci]  = (kz <= 2) && (ky <= 2) && (kx <= 2) &&
                          ((unsigned)olz < TILE) && ((unsigned)oly < TILE) &&
                          ((unsigned)olx < TILE);
                pre[ci] = (((kz * 3 + ky) * 3 + kx) << 6) | ((olz * TILE + oly) * TILE + olx);
            }
            for (; j >= 0; j = nxt[j]) {
                #pragma unroll
                for (int ci = 0; ci < 8; ++ci) {
                    if (ok[ci]) {
                        const int s = atomicAdd(&cnt, 1);
                        if (s < CAP) list[s] = (j << 11) | pre[ci];
                    }
                }
            }
        }
        __syncthreads();                     // B: list complete

        // Phase 2: wave-per-pair. W from LDS (conflict-free b32), feats 1 line.
        const int m = min(cnt, CAP);
        #pragma unroll 2
        for (int i = wv; i < m; i += 8) {
            const int e = list[i];
            const int vox = e & 63, k = (e >> 6) & 31, j = e >> 11;
            const float4* fp = (const float4*)(feats + (size_t)j * CIN);
            float4 f[8];
            #pragma unroll
            for (int q = 0; q < 8; ++q) f[q] = fp[q];
            const float2* g = (const float2*)f;
            const unsigned* wb = wfu + (k << 10) + ch;
            float s0 = 0.f, s1 = 0.f;
            #pragma unroll
            for (int cp = 0; cp < 16; ++cp) {
                const unsigned u = wb[cp << 6];          // lane stride 4B: banks 0..31
                const float2 gq = g[cp];
                s0 += gq.x * __uint_as_float(u << 16);
                s1 += gq.y * __uint_as_float(u & 0xffff0000u);
            }
            unsafeAtomicAdd(&accf[vox * COUT + ch], s0 + s1);   // ds_add, stride-1
        }
        __syncthreads();                     // C: accumulation done

        // Phase 3: write tile (16 rows x 256 contiguous f32) + rezero own words.
        #pragma unroll
        for (int it = 0; it < 2; ++it) {
            const int i4 = (it * NTH + tid) * 4;
            float4 v = *(float4*)(accf + i4);
            *(float4*)(accf + i4) = make_float4(0.f, 0.f, 0.f, 0.f);
            const int row = i4 >> 8;
            const int vz = row >> 2, vy = row & 3;
            const int inrow = i4 & 255;
            const size_t gidx = ((((size_t)b * OUTD + (oz0 + vz)) * OUTD + (oy0 + vy)) * OUTD + ox0) * COUT + inrow;
            *(float4*)(out + gidx) = v;
        }
        if (tid == 0) cnt = 0;               // ordered vs next phase1 by sync A
    }
}

// ---------- fallback A (ws >= 110 KB): R7 champion scatter ----------
__device__ __forceinline__ int axis_opts(int p, int* k, int* o) {
    int cnt = 0;
    const int kp = (p + 1) & 1;
    const int o0 = (p + 1 - kp) >> 1;
    if (o0 < OUTD) { k[cnt] = kp; o[cnt] = o0; ++cnt; }
    if (kp == 0) { const int o1 = o0 - 1; if (o1 >= 0) { k[cnt] = 2; o[cnt] = o1; ++cnt; } }
    return cnt;
}

__global__ void conv_w_bf16(const float* __restrict__ W, ushort* __restrict__ wsW)
{
    const int k = blockIdx.x;
    for (int i = threadIdx.x; i < CIN * COUT; i += 256) {
        const int c = i >> 6, chh = i & 63;
        const unsigned u = __float_as_uint(W[k * CIN * COUT + i]);
        const unsigned r = (u + 0x7fffu + ((u >> 16) & 1u)) >> 16;
        wsW[(k << 11) + (chh << 5) + c] = (ushort)r;
    }
}

__global__ __launch_bounds__(256) void scatter2(
    const float* __restrict__ feats, const ushort* __restrict__ wsW,
    const int4* __restrict__ coors, float* __restrict__ out,
    int N, int totWaves)
{
    const int chh = threadIdx.x & 63;
    const int wv = __builtin_amdgcn_readfirstlane(threadIdx.x >> 6);
    const int gwave = blockIdx.x * 4 + wv;
    for (int i = gwave; i < N; i += totWaves) {
        const int4 c = coors[i];
        const float4* fp = (const float4*)(feats + (size_t)i * CIN);
        float4 f[8];
        #pragma unroll
        for (int q = 0; q < 8; ++q) f[q] = fp[q];
        int kz[2], oz[2], ky[2], oy[2], kx[2], ox[2];
        const int nz = axis_opts(c.y, kz, oz);
        const int ny = axis_opts(c.z, ky, oy);
        const int nx = axis_opts(c.w, kx, ox);
        for (int az = 0; az < nz; ++az)
        for (int ay = 0; ay < ny; ++ay)
        for (int ax = 0; ax < nx; ++ax) {
            const int kidx = (kz[az] * 3 + ky[ay]) * 3 + kx[ax];
            const uint4* wp = (const uint4*)(wsW + (kidx << 11) + (chh << 5));
            uint4 w4[4];
            #pragma unroll
            for (int q = 0; q < 4; ++q) w4[q] = wp[q];
            float s0 = 0.f, s1 = 0.f;
            #pragma unroll
            for (int q = 0; q < 4; ++q) {
                const uint4 wq = w4[q];
                const float4 fa = f[2 * q], fb = f[2 * q + 1];
                s0 += fa.x * __uint_as_float(wq.x << 16);
                s1 += fa.y * __uint_as_float(wq.x & 0xffff0000u);
                s0 += fa.z * __uint_as_float(wq.y << 16);
                s1 += fa.w * __uint_as_float(wq.y & 0xffff0000u);
                s0 += fb.x * __uint_as_float(wq.z << 16);
                s1 += fb.y * __uint_as_float(wq.z & 0xffff0000u);
                s0 += fb.z * __uint_as_float(wq.w << 16);
                s1 += fb.w * __uint_as_float(wq.w & 0xffff0000u);
            }
            const size_t flat = (((size_t)c.x * OUTD + oz[az]) * OUTD + oy[ay]) * OUTD + ox[ax];
            unsafeAtomicAdd(out + flat * COUT + chh, s0 + s1);
        }
    }
}

// ---------- last-resort fallback ----------
__global__ __launch_bounds__(256, 4) void spconv_scatter(
    const float* __restrict__ feats, const float* __restrict__ Wt,
    const int* __restrict__ coors, float* __restrict__ out, int N)
{
    __shared__ float sf[NPTS][CIN];
    __shared__ int   sc[NPTS][4];
    __shared__ int   vf[NPTS];
    const int tid = threadIdx.x;
    const int chh = tid & 63;
    const int wv  = tid >> 6;
    const int base = blockIdx.x * NPTS;
    const int npts = min(NPTS, (int)(N - base));
    if (npts <= 0) return;
    for (int i = tid; i < npts * CIN; i += 256) sf[0][i] = feats[base * CIN + i];
    for (int i = tid; i < npts * 4; i += 256) ((int*)sc)[i] = coors[base * 4 + i];
    __syncthreads();
    for (int off = 0; off < 27; ++off) {
        const int kz = off / 9, ky = (off / 3) % 3, kx = off % 3;
        if (tid < npts) {
            const int p  = tid;
            const int nz = sc[p][1] + 1 - kz;
            const int ny = sc[p][2] + 1 - ky;
            const int nx = sc[p][3] + 1 - kx;
            const int m  = nz | ny | nx;
            const int oz = nz >> 1, oy = ny >> 1, ox = nx >> 1;
            const bool v = ((m & 0x80000001) == 0) &&
                           (oz < OUTD) && (oy < OUTD) && (ox < OUTD);
            vf[p] = v ? (((sc[p][0] * OUTD + oz) * OUTD + oy) * OUTD + ox) : -1;
        }
        const float* wp = Wt + off * (CIN * COUT) + chh;
        float w[CIN];
        #pragma unroll
        for (int c = 0; c < CIN; ++c) w[c] = wp[c * COUT];
        __syncthreads();
        for (int p = wv; p < npts; p += 4) {
            const int f = vf[p];
            if (f >= 0) {
                float s = 0.f;
                #pragma unroll
                for (int c = 0; c < CIN; ++c) s += sf[p][c] * w[c];
                atomicAdd(&out[(size_t)f * COUT + chh], s);
            }
        }
        __syncthreads();
    }
}

extern "C" void kernel_launch(void* const* d_in, const int* in_sizes, int n_in,
                              void* d_out, int out_size, void* d_ws, size_t ws_size,
                              hipStream_t stream) {
    const float* feats = (const float*)d_in[0];
    const float* Wt    = (const float*)d_in[1];
    const int*   coors = (const int*)d_in[2];
    float*       out   = (float*)d_out;

    const int N = in_sizes[0] / CIN;
    const int B = out_size / (OUTD * OUTD * OUTD * COUT);

    const size_t mapElems = (size_t)B * IND * IND * IND;
    const size_t needMap  = (mapElems + (size_t)N) * sizeof(int);
    const size_t needBf   = 27 * CIN * COUT * sizeof(ushort);

    if (ws_size >= needMap) {
        int* map = (int*)d_ws;
        int* nxt = map + mapElems;
        hipMemsetAsync(map, 0xFF, mapElems * sizeof(int), stream);
        build_map<<<(N + 255) / 256, 256, 0, stream>>>((const int4*)coors, map, nxt, N);
        const int nT = B * NTILE * NTILE * NTILE;
        gather_p<<<GRID, NTH, 0, stream>>>(feats, Wt, map, nxt, out, nT);
    } else if (ws_size >= needBf) {
        hipMemsetAsync(d_out, 0, (size_t)out_size * sizeof(float), stream);
        ushort* wsW = (ushort*)d_ws;
        conv_w_bf16<<<27, 256, 0, stream>>>(Wt, wsW);
        scatter2<<<NBLK, 256, 0, stream>>>(feats, wsW, (const int4*)coors, out, N, NBLK * 4);
    } else {
        hipMemsetAsync(d_out, 0, (size_t)out_size * sizeof(float), stream);
        spconv_scatter<<<(N + NPTS - 1) / NPTS, 256, 0, stream>>>(feats, Wt, coors, out, N);
    }
}

// Round 14
// 195.922 us; speedup vs baseline: 1.5367x; 1.5367x over previous
//
#include <hip/hip_runtime.h>

// Sparse 3D conv (K=3, stride=2, pad=1), dense output, K-OUTER TILE GATHER.
// Key fact: for fixed kernel offset k, output voxel o receives from exactly one
// input position p = 2o-1+k. A block owning a 2-tile (2 x 4x4x4) output chunk
// loops k=0..26 (split over its 4 waves), stages W[k] once in registers, probes
// the 64-point input lattice with ONE lane-vectorized map load, and wave-dots
// each hit into a 32 KB LDS accumulator. No global atomics, no output memset,
// no pair lists, no 9^3 scans. Exactly-once coalesced output writes.
// Inputs: features [N,32] f32, W [3,3,3,32,64] f32, coors [N,4] i32 (b,z,y,x).
// ws: [ map B*128^3 i32 | nxt N i32 | W_bf16 27*64*32 ushort ]

#define CIN   32
#define COUT  64
#define OUTD  64
#define IND   128
#define TILE  4
#define GRID  2048
#define NTH   256
#define NPTS  128
#define NBLK  2048

// ---------- map build: voxel -> head of point-index chain (R3-verified) ----------
__global__ void build_map(const int4* __restrict__ coors, int* __restrict__ map,
                          int* __restrict__ nxt, int N)
{
    int i = blockIdx.x * 256 + threadIdx.x;
    if (i >= N) return;
    const int4 c = coors[i];                       // (b, z, y, x)
    const int v = ((c.x * IND + c.y) * IND + c.z) * IND + c.w;
    nxt[i] = atomicExch(&map[v], i);
}

// ---------- W transpose+quantize: [27][32][64] f32 -> [27][64][32] bf16 ----------
__global__ void conv_w_bf16(const float* __restrict__ W, ushort* __restrict__ wsW)
{
    const int k = blockIdx.x;
    for (int i = threadIdx.x; i < CIN * COUT; i += 256) {
        const int c = i >> 6, chh = i & 63;
        const unsigned u = __float_as_uint(W[k * CIN * COUT + i]);
        const unsigned r = (u + 0x7fffu + ((u >> 16) & 1u)) >> 16;   // RNE
        wsW[(k << 11) + (chh << 5) + c] = (ushort)r;
    }
}

// ---------- k-outer gather: block = 2 output tiles, persistent ----------
__global__ __launch_bounds__(NTH) void gather_k(
    const float* __restrict__ feats, const ushort* __restrict__ wsW,
    const int* __restrict__ map, const int* __restrict__ nxt,
    float* __restrict__ out, int nUnits)
{
    __shared__ float acc[2 * 64 * COUT];           // 32 KB: [half][vox][ch]

    const int tid = threadIdx.x;
    const int ch  = tid & 63;                      // lane = out channel = voxel id
    const int wv  = tid >> 6;                      // wave 0..3
    // lane's probe voxel within a tile: L = vz*16 + vy*4 + vx
    const int vz = ch >> 4, vy = (ch >> 2) & 3, vx = ch & 3;

    for (int u = blockIdx.x; u < nUnits; u += GRID) {
        for (int i = tid; i < 2 * 64 * COUT; i += NTH) acc[i] = 0.f;
        __syncthreads();                           // A: acc zeroed

        // wave wv handles k = wv, wv+4, ..., <27
        for (int k = wv; k < 27; k += 4) {
            const int kz = k / 9, ky = (k / 3) % 3, kx = k % 3;
            // stage W[k] for this wave: 4 x uint4 = 32 bf16 (R7-proven layout)
            const uint4* wp = (const uint4*)(wsW + (k << 11) + (ch << 5));
            uint4 w4[4];
            #pragma unroll
            for (int q = 0; q < 4; ++q) w4[q] = wp[q];

            #pragma unroll
            for (int half = 0; half < 2; ++half) {
                int tt = 2 * u + half;
                const int ox0 = (tt & 15) * TILE; tt >>= 4;
                const int oy0 = (tt & 15) * TILE; tt >>= 4;
                const int oz0 = (tt & 15) * TILE; tt >>= 4;
                const int b   = tt;

                const int px = 2 * (ox0 + vx) - 1 + kx;
                const int py = 2 * (oy0 + vy) - 1 + ky;
                const int pz = 2 * (oz0 + vz) - 1 + kz;
                int j = -1;
                if ((unsigned)px < IND && (unsigned)py < IND && (unsigned)pz < IND)
                    j = map[((b * IND + pz) * IND + py) * IND + px];

                for (unsigned long long m = __ballot(j >= 0); m; m &= m - 1) {
                    const int L = __builtin_ctzll(m);      // hit lane = voxel id
                    int jj = __shfl(j, L);                  // point index (uniform)
                    const int aoff = half * 4096 + L * 64 + ch;
                    while (jj >= 0) {                       // duplicate-coord chain
                        const float4* fp = (const float4*)(feats + (size_t)jj * CIN);
                        float4 f[8];
                        #pragma unroll
                        for (int q = 0; q < 8; ++q) f[q] = fp[q];   // broadcast row
                        float s0 = 0.f, s1 = 0.f;
                        #pragma unroll
                        for (int q = 0; q < 4; ++q) {
                            const uint4 wq = w4[q];
                            const float4 fa = f[2 * q], fb = f[2 * q + 1];
                            s0 += fa.x * __uint_as_float(wq.x << 16);
                            s1 += fa.y * __uint_as_float(wq.x & 0xffff0000u);
                            s0 += fa.z * __uint_as_float(wq.y << 16);
                            s1 += fa.w * __uint_as_float(wq.y & 0xffff0000u);
                            s0 += fb.x * __uint_as_float(wq.z << 16);
                            s1 += fb.y * __uint_as_float(wq.z & 0xffff0000u);
                            s0 += fb.z * __uint_as_float(wq.w << 16);
                            s1 += fb.w * __uint_as_float(wq.w & 0xffff0000u);
                        }
                        unsafeAtomicAdd(&acc[aoff], s0 + s1);   // ds_add, stride-1
                        jj = nxt[jj];
                    }
                }
            }
        }
        __syncthreads();                           // B: all k accumulated

        // Write both tiles: 32 rows x 256 contiguous floats, exactly once.
        #pragma unroll
        for (int it = 0; it < 8; ++it) {
            const int i4 = (it * NTH + tid) * 4;
            int tt = 2 * u + (i4 >> 12);
            const int ox0 = (tt & 15) * TILE; tt >>= 4;
            const int oy0 = (tt & 15) * TILE; tt >>= 4;
            const int oz0 = (tt & 15) * TILE; tt >>= 4;
            const int b   = tt;
            const int inner = i4 & 4095;
            const int row = inner >> 8;            // vz*4+vy
            const int rvz = row >> 2, rvy = row & 3;
            const int inrow = inner & 255;
            const size_t g = ((((size_t)b * OUTD + (oz0 + rvz)) * OUTD + (oy0 + rvy)) * OUTD + ox0) * COUT + inrow;
            *(float4*)(out + g) = *(const float4*)(acc + i4);
        }
        __syncthreads();                           // C: writes read acc before rezero
    }
}

// ---------- fallback A (ws >= 110 KB): R7 champion scatter ----------
__device__ __forceinline__ int axis_opts(int p, int* k, int* o) {
    int cnt = 0;
    const int kp = (p + 1) & 1;
    const int o0 = (p + 1 - kp) >> 1;
    if (o0 < OUTD) { k[cnt] = kp; o[cnt] = o0; ++cnt; }
    if (kp == 0) { const int o1 = o0 - 1; if (o1 >= 0) { k[cnt] = 2; o[cnt] = o1; ++cnt; } }
    return cnt;
}

__global__ __launch_bounds__(256) void scatter2(
    const float* __restrict__ feats, const ushort* __restrict__ wsW,
    const int4* __restrict__ coors, float* __restrict__ out,
    int N, int totWaves)
{
    const int chh = threadIdx.x & 63;
    const int wv = __builtin_amdgcn_readfirstlane(threadIdx.x >> 6);
    const int gwave = blockIdx.x * 4 + wv;
    for (int i = gwave; i < N; i += totWaves) {
        const int4 c = coors[i];
        const float4* fp = (const float4*)(feats + (size_t)i * CIN);
        float4 f[8];
        #pragma unroll
        for (int q = 0; q < 8; ++q) f[q] = fp[q];
        int kz[2], oz[2], ky[2], oy[2], kx[2], ox[2];
        const int nz = axis_opts(c.y, kz, oz);
        const int ny = axis_opts(c.z, ky, oy);
        const int nx = axis_opts(c.w, kx, ox);
        for (int az = 0; az < nz; ++az)
        for (int ay = 0; ay < ny; ++ay)
        for (int ax = 0; ax < nx; ++ax) {
            const int kidx = (kz[az] * 3 + ky[ay]) * 3 + kx[ax];
            const uint4* wp = (const uint4*)(wsW + (kidx << 11) + (chh << 5));
            uint4 w4[4];
            #pragma unroll
            for (int q = 0; q < 4; ++q) w4[q] = wp[q];
            float s0 = 0.f, s1 = 0.f;
            #pragma unroll
            for (int q = 0; q < 4; ++q) {
                const uint4 wq = w4[q];
                const float4 fa = f[2 * q], fb = f[2 * q + 1];
                s0 += fa.x * __uint_as_float(wq.x << 16);
                s1 += fa.y * __uint_as_float(wq.x & 0xffff0000u);
                s0 += fa.z * __uint_as_float(wq.y << 16);
                s1 += fa.w * __uint_as_float(wq.y & 0xffff0000u);
                s0 += fb.x * __uint_as_float(wq.z << 16);
                s1 += fb.y * __uint_as_float(wq.z & 0xffff0000u);
                s0 += fb.z * __uint_as_float(wq.w << 16);
                s1 += fb.w * __uint_as_float(wq.w & 0xffff0000u);
            }
            const size_t flat = (((size_t)c.x * OUTD + oz[az]) * OUTD + oy[ay]) * OUTD + ox[ax];
            unsafeAtomicAdd(out + flat * COUT + chh, s0 + s1);
        }
    }
}

// ---------- last-resort fallback ----------
__global__ __launch_bounds__(256, 4) void spconv_scatter(
    const float* __restrict__ feats, const float* __restrict__ Wt,
    const int* __restrict__ coors, float* __restrict__ out, int N)
{
    __shared__ float sf[NPTS][CIN];
    __shared__ int   sc[NPTS][4];
    __shared__ int   vf[NPTS];
    const int tid = threadIdx.x;
    const int chh = tid & 63;
    const int wv  = tid >> 6;
    const int base = blockIdx.x * NPTS;
    const int npts = min(NPTS, (int)(N - base));
    if (npts <= 0) return;
    for (int i = tid; i < npts * CIN; i += 256) sf[0][i] = feats[base * CIN + i];
    for (int i = tid; i < npts * 4; i += 256) ((int*)sc)[i] = coors[base * 4 + i];
    __syncthreads();
    for (int off = 0; off < 27; ++off) {
        const int kz = off / 9, ky = (off / 3) % 3, kx = off % 3;
        if (tid < npts) {
            const int p  = tid;
            const int nz = sc[p][1] + 1 - kz;
            const int ny = sc[p][2] + 1 - ky;
            const int nx = sc[p][3] + 1 - kx;
            const int m  = nz | ny | nx;
            const int oz = nz >> 1, oy = ny >> 1, ox = nx >> 1;
            const bool v = ((m & 0x80000001) == 0) &&
                           (oz < OUTD) && (oy < OUTD) && (ox < OUTD);
            vf[p] = v ? (((sc[p][0] * OUTD + oz) * OUTD + oy) * OUTD + ox) : -1;
        }
        const float* wp = Wt + off * (CIN * COUT) + chh;
        float w[CIN];
        #pragma unroll
        for (int c = 0; c < CIN; ++c) w[c] = wp[c * COUT];
        __syncthreads();
        for (int p = wv; p < npts; p += 4) {
            const int f = vf[p];
            if (f >= 0) {
                float s = 0.f;
                #pragma unroll
                for (int c = 0; c < CIN; ++c) s += sf[p][c] * w[c];
                atomicAdd(&out[(size_t)f * COUT + chh], s);
            }
        }
        __syncthreads();
    }
}

extern "C" void kernel_launch(void* const* d_in, const int* in_sizes, int n_in,
                              void* d_out, int out_size, void* d_ws, size_t ws_size,
                              hipStream_t stream) {
    const float* feats = (const float*)d_in[0];
    const float* Wt    = (const float*)d_in[1];
    const int*   coors = (const int*)d_in[2];
    float*       out   = (float*)d_out;

    const int N = in_sizes[0] / CIN;
    const int B = out_size / (OUTD * OUTD * OUTD * COUT);

    const size_t mapElems = (size_t)B * IND * IND * IND;
    const size_t nxtPad   = ((size_t)N + 3) & ~(size_t)3;
    const size_t wOfs     = mapElems + nxtPad;                     // int units
    const size_t needMap  = (wOfs + (27 * CIN * COUT + 1) / 2) * sizeof(int);
    const size_t needBf   = 27 * CIN * COUT * sizeof(ushort);

    if (ws_size >= needMap) {
        int*    map = (int*)d_ws;
        int*    nxt = map + mapElems;
        ushort* wsW = (ushort*)(map + wOfs);
        hipMemsetAsync(map, 0xFF, mapElems * sizeof(int), stream);
        build_map<<<(N + 255) / 256, 256, 0, stream>>>((const int4*)coors, map, nxt, N);
        conv_w_bf16<<<27, 256, 0, stream>>>(Wt, wsW);
        const int nUnits = (B * 16 * 16 * 16) / 2;   // 4096 for B=2
        gather_k<<<GRID, NTH, 0, stream>>>(feats, wsW, map, nxt, out, nUnits);
    } else if (ws_size >= needBf) {
        hipMemsetAsync(d_out, 0, (size_t)out_size * sizeof(float), stream);
        ushort* wsW = (ushort*)d_ws;
        conv_w_bf16<<<27, 256, 0, stream>>>(Wt, wsW);
        scatter2<<<NBLK, 256, 0, stream>>>(feats, wsW, (const int4*)coors, out, N, NBLK * 4);
    } else {
        hipMemsetAsync(d_out, 0, (size_t)out_size * sizeof(float), stream);
        spconv_scatter<<<(N + NPTS - 1) / NPTS, 256, 0, stream>>>(feats, Wt, coors, out, N);
    }
}

// Round 15
// 142.240 us; speedup vs baseline: 2.1166x; 1.3774x over previous
//
#include <hip/hip_runtime.h>

// Sparse 3D conv (K=3, stride=2, pad=1), dense output, direct per-point scatter.
// R7 champion structure restored (133 us total): persistent 2048-block grid,
// one wave per point, 64 lanes = 64 out channels, bf16 W pre-transposed to
// [27][64][32] (64B lane stride = 2 lanes/line), <=8 posted atomics per point.
// Delta vs R7: #pragma unroll 2 on the point loop -> two independent
// load->dot->atomic chains in flight per wave (static indexing, no scratch).
// Inputs: features [N,32] f32, W [3,3,3,32,64] f32, coors [N,4] i32 (b,z,y,x).
// Output: [B,64,64,64,64] f32 flat (memset to 0, then posted atomic adds).
// ws: [ W_bf16 27*64*32 ushort ]  (~110 KB)

#define CIN   32
#define COUT  64
#define OUTD  64
#define NBLK  2048
#define NPTS  128

// Valid (k, o) options along one axis: o = (p+1-k)/2, parity-matched, 0<=o<64.
// Arrays only indexed by the 2-bounded unrolled loop vars -> stay in registers.
__device__ __forceinline__ int axis_opts(int p, int* k, int* o) {
    int cnt = 0;
    const int kp = (p + 1) & 1;          // smallest parity-matching k
    const int o0 = (p + 1 - kp) >> 1;    // >= 0 always
    if (o0 < OUTD) { k[cnt] = kp; o[cnt] = o0; ++cnt; }
    if (kp == 0) {                       // k=2 shares parity with k=0
        const int o1 = o0 - 1;
        if (o1 >= 0) { k[cnt] = 2; o[cnt] = o1; ++cnt; }
    }
    return cnt;
}

// ---------- W transpose+quantize: [27][32][64] f32 -> [27][64][32] bf16 ----------
__global__ void conv_w_bf16(const float* __restrict__ W, ushort* __restrict__ wsW)
{
    const int k = blockIdx.x;            // 27 blocks
    for (int i = threadIdx.x; i < CIN * COUT; i += 256) {
        const int c = i >> 6, ch = i & 63;
        const unsigned u = __float_as_uint(W[k * CIN * COUT + i]);
        const unsigned r = (u + 0x7fffu + ((u >> 16) & 1u)) >> 16;   // RNE
        wsW[(k << 11) + (ch << 5) + c] = (ushort)r;
    }
}

// ---------- scatter: persistent waves, posted global atomics ----------
__global__ __launch_bounds__(256) void scatter2(
    const float* __restrict__ feats, const ushort* __restrict__ wsW,
    const int4* __restrict__ coors, float* __restrict__ out,
    int N, int totWaves)
{
    const int ch = threadIdx.x & 63;
    const int wv = __builtin_amdgcn_readfirstlane(threadIdx.x >> 6);
    const int gwave = blockIdx.x * 4 + wv;

    #pragma unroll 2
    for (int i = gwave; i < N; i += totWaves) {
        const int4 c = coors[i];                         // wave-uniform
        const float4* fp = (const float4*)(feats + (size_t)i * CIN);
        float4 f[8];
        #pragma unroll
        for (int q = 0; q < 8; ++q) f[q] = fp[q];        // broadcast row

        int kz[2], oz[2], ky[2], oy[2], kx[2], ox[2];
        const int nz = axis_opts(c.y, kz, oz);
        const int ny = axis_opts(c.z, ky, oy);
        const int nx = axis_opts(c.w, kx, ox);

        for (int az = 0; az < nz; ++az)
        for (int ay = 0; ay < ny; ++ay)
        for (int ax = 0; ax < nx; ++ax) {
            const int kidx = (kz[az] * 3 + ky[ay]) * 3 + kx[ax];
            const uint4* wp = (const uint4*)(wsW + (kidx << 11) + (ch << 5));
            uint4 w4[4];
            #pragma unroll
            for (int q = 0; q < 4; ++q) w4[q] = wp[q];   // 64B/lane, 2 lanes/line
            float s0 = 0.f, s1 = 0.f;                    // two chains
            #pragma unroll
            for (int q = 0; q < 4; ++q) {
                const uint4 wq = w4[q];
                const float4 fa = f[2 * q], fb = f[2 * q + 1];
                s0 += fa.x * __uint_as_float(wq.x << 16);
                s1 += fa.y * __uint_as_float(wq.x & 0xffff0000u);
                s0 += fa.z * __uint_as_float(wq.y << 16);
                s1 += fa.w * __uint_as_float(wq.y & 0xffff0000u);
                s0 += fb.x * __uint_as_float(wq.z << 16);
                s1 += fb.y * __uint_as_float(wq.z & 0xffff0000u);
                s0 += fb.z * __uint_as_float(wq.w << 16);
                s1 += fb.w * __uint_as_float(wq.w & 0xffff0000u);
            }
            const size_t flat = (((size_t)c.x * OUTD + oz[az]) * OUTD + oy[ay]) * OUTD + ox[ax];
            unsafeAtomicAdd(out + flat * COUT + ch, s0 + s1);   // posted, no return
        }
    }
}

// ---------- fallback (ws too small for even W): round-1 scatter ----------
__global__ __launch_bounds__(256, 4) void spconv_scatter(
    const float* __restrict__ feats, const float* __restrict__ Wt,
    const int* __restrict__ coors, float* __restrict__ out, int N)
{
    __shared__ float sf[NPTS][CIN];
    __shared__ int   sc[NPTS][4];
    __shared__ int   vf[NPTS];

    const int tid = threadIdx.x;
    const int ch  = tid & 63;
    const int wv  = tid >> 6;
    const int base = blockIdx.x * NPTS;
    const int npts = min(NPTS, (int)(N - base));
    if (npts <= 0) return;

    for (int i = tid; i < npts * CIN; i += 256) sf[0][i] = feats[base * CIN + i];
    for (int i = tid; i < npts * 4; i += 256) ((int*)sc)[i] = coors[base * 4 + i];
    __syncthreads();

    for (int off = 0; off < 27; ++off) {
        const int kz = off / 9, ky = (off / 3) % 3, kx = off % 3;
        if (tid < npts) {
            const int p  = tid;
            const int nz = sc[p][1] + 1 - kz;
            const int ny = sc[p][2] + 1 - ky;
            const int nx = sc[p][3] + 1 - kx;
            const int m  = nz | ny | nx;
            const int oz = nz >> 1, oy = ny >> 1, ox = nx >> 1;
            const bool v = ((m & 0x80000001) == 0) &&
                           (oz < OUTD) && (oy < OUTD) && (ox < OUTD);
            vf[p] = v ? (((sc[p][0] * OUTD + oz) * OUTD + oy) * OUTD + ox) : -1;
        }
        const float* wp = Wt + off * (CIN * COUT) + ch;
        float w[CIN];
        #pragma unroll
        for (int c = 0; c < CIN; ++c) w[c] = wp[c * COUT];
        __syncthreads();
        for (int p = wv; p < npts; p += 4) {
            const int f = vf[p];
            if (f >= 0) {
                float s = 0.f;
                #pragma unroll
                for (int c = 0; c < CIN; ++c) s += sf[p][c] * w[c];
                atomicAdd(&out[(size_t)f * COUT + ch], s);
            }
        }
        __syncthreads();
    }
}

extern "C" void kernel_launch(void* const* d_in, const int* in_sizes, int n_in,
                              void* d_out, int out_size, void* d_ws, size_t ws_size,
                              hipStream_t stream) {
    const float* feats = (const float*)d_in[0];
    const float* Wt    = (const float*)d_in[1];
    const int*   coors = (const int*)d_in[2];
    float*       out   = (float*)d_out;

    const int N = in_sizes[0] / CIN;

    hipMemsetAsync(d_out, 0, (size_t)out_size * sizeof(float), stream);

    const size_t need = 27 * CIN * COUT * sizeof(ushort);
    if (ws_size >= need) {
        ushort* wsW = (ushort*)d_ws;
        conv_w_bf16<<<27, 256, 0, stream>>>(Wt, wsW);
        scatter2<<<NBLK, 256, 0, stream>>>(feats, wsW, (const int4*)coors, out, N, NBLK * 4);
    } else {
        spconv_scatter<<<(N + NPTS - 1) / NPTS, 256, 0, stream>>>(feats, Wt, coors, out, N);
    }
}